// Round 1
// baseline (815.972 us; speedup 1.0000x reference)
//
#include <hip/hip_runtime.h>

// ActiveParticles forward pass, N=4096, float32.
// Constants mirror the Python reference exactly (double math -> f32 cast).
#define NPART 4096
#define PI_F 3.1415927410125732f
#define TWO_PI_F 6.2831854820251465f   // 2*PI_F (exact, pow2 scale)
#define HALF_PI_F 1.5707963705062866f  // PI_F/2 (exact)

__device__ __forceinline__ float wrapf(float d) {
    // replicates: d = where(d <= -PI, mod(d, PI), d); d -= (d >= PI)*2PI
    if (d <= -PI_F) {
        d = fmodf(d, PI_F);          // C fmod == lax.rem
        if (d < 0.0f) d += PI_F;     // python-mod sign fixup
    }
    if (d >= PI_F) d -= TWO_PI_F;
    return d;
}

// ---------------- K0: per-particle orientation angle ----------------
__global__ void k_ang(const float* __restrict__ orr, const float* __restrict__ oim,
                      float* __restrict__ ang) {
    int i = blockIdx.x * 256 + threadIdx.x;
    ang[i] = atan2f(oim[i], orr[i]);
}

// ---------------- K1: global center of mass (Ra = inf) ----------------
__global__ void k_cms(const float* __restrict__ pr, const float* __restrict__ pim,
                      float* __restrict__ cms) {
    __shared__ float sr[256], si[256];
    int t = threadIdx.x;
    float a = 0.0f, b = 0.0f;
    for (int k = t; k < NPART; k += 256) { a += pr[k]; b += pim[k]; }
    sr[t] = a; si[t] = b;
    __syncthreads();
    for (int s = 128; s > 0; s >>= 1) {
        if (t < s) { sr[t] += sr[t + s]; si[t] += si[t + s]; }
        __syncthreads();
    }
    if (t == 0) { cms[0] = sr[0] / 4096.0f; cms[1] = si[0] / 4096.0f; }
}

// ---------------- K2: interaction pass ----------------
// 256 blocks x 256 threads; block owns 16 particles i, 16 j-slices each.
__global__ void k_interact(const float* __restrict__ pr, const float* __restrict__ pim,
                           const float* __restrict__ orr, const float* __restrict__ oim,
                           const float* __restrict__ ang,
                           const float* __restrict__ deltas,
                           const float* __restrict__ rot_noise,
                           const float* __restrict__ tn_re, const float* __restrict__ tn_im,
                           const float* __restrict__ cms,
                           float* __restrict__ out,
                           float* __restrict__ p0_re, float* __restrict__ p0_im) {
    constexpr float RR_F  = 8e-6f;
    constexpr float ROC_F = (float)(2.5e-5 + 3.15e-6);     // RO + RC
    __shared__ float ls_pr[256], ls_pi[256], ls_an[256], ls_or[256], ls_oi[256];
    __shared__ float red[256 * 5];

    int tid = threadIdx.x;
    int li = tid & 15, sl = tid >> 4;
    int i = blockIdx.x * 16 + li;

    float pi_re = pr[i], pi_im = pim[i], ai = ang[i];
    float n_r = 0.0f, S_re = 0.0f, S_im = 0.0f, o_re = 0.0f, o_im = 0.0f;

    for (int c = 0; c < NPART / 256; ++c) {
        int j0 = c * 256;
        __syncthreads();
        ls_pr[tid] = pr[j0 + tid]; ls_pi[tid] = pim[j0 + tid];
        ls_an[tid] = ang[j0 + tid];
        ls_or[tid] = orr[j0 + tid]; ls_oi[tid] = oim[j0 + tid];
        __syncthreads();
#pragma unroll
        for (int t = 0; t < 16; ++t) {
            int jj = sl * 16 + t;
            int j = j0 + jj;
            float dr = pi_re - ls_pr[jj];
            float di = pi_im - ls_pi[jj];
            float h = hypotf(dr, di);                      // match complex abs
            bool wro = (h <= ROC_F) || (j == i);           // orientation zone incl. self
            if (wro) { o_re += ls_or[jj]; o_im += ls_oi[jj]; }
            float ad = wrapf(ai - ls_an[jj]);
            bool infront = fabsf(ad) < HALF_PI_F;
            bool wrr = (h <= RR_F) && (j != i) && infront; // repulsion zone
            if (wrr) { n_r += 1.0f; S_re += ls_pr[jj]; S_im += ls_pi[jj]; }
        }
    }

    red[tid] = n_r; red[256 + tid] = S_re; red[512 + tid] = S_im;
    red[768 + tid] = o_re; red[1024 + tid] = o_im;
    __syncthreads();

    if (tid < 16) {   // li == tid, sl == 0: epilogue per particle
        for (int s = 1; s < 16; ++s) {
            int t2 = (s << 4) | tid;
            n_r += red[t2]; S_re += red[256 + t2]; S_im += red[512 + t2];
            o_re += red[768 + t2]; o_im += red[1024 + t2];
        }
        float maxnr = fmaxf(n_r, 1.0f);
        float sgn = (n_r > 0.0f) ? 1.0f : 0.0f;
        float Sre = S_re / maxnr - pi_re * sgn;
        float Sim = S_im / maxnr - pi_im * sgn;
        float d_re = -Sre, d_im = -Sim;

        float Ps_re = cms[0] - pi_re;                      // n_a = 4096 > 0
        float Ps_im = cms[1] - pi_im;

        float dl = deltas[i];
        float cd = cosf(dl), sd = sinf(dl);
        float l_re = Ps_re * cd - Ps_im * sd;              // Ps * e^{+i d}
        float l_im = Ps_re * sd + Ps_im * cd;
        float r_re = Ps_re * cd + Ps_im * sd;              // Ps * e^{-i d}
        float r_im = Ps_im * cd - Ps_re * sd;

        float nb = fmaxf(hypotf(o_re, o_im), 1e-14f);
        float na_l = fmaxf(hypotf(l_re, l_im), 1e-14f);
        float na_r = fmaxf(hypotf(r_re, r_im), 1e-14f);
        float csl = (l_re * o_re + l_im * o_im) / (na_l * nb);
        float csr = (r_re * o_re + r_im * o_im) / (na_r * nb);
        float b_re = (csl >= csr) ? l_re : r_re;
        float b_im = (csl >= csr) ? l_im : r_im;

        bool has_rep = (d_re != 0.0f) || (d_im != 0.0f);   // |d| > 0
        float att;
        if (has_rep) att = wrapf(atan2f(d_im, d_re) - ai);
        else         att = wrapf(atan2f(b_im, b_re) - ai);

        constexpr float GDD  = (float)(0.2 * 25.0 * 0.0028);           // DT*GAMMA*DR
        constexpr float S2DR = 0.07483314773547883f;                    // sqrt(2*DR)
        constexpr float SDT  = 0.44721359549995793f;                    // sqrt(DT)
        float theta = GDD * sinf(att) + (rot_noise[i] * S2DR) * SDT;
        float rr_ = cosf(theta), ri_ = sinf(theta);

        float oi_re = orr[i], oi_im = oim[i];
        float no_re = oi_re * rr_ - oi_im * ri_;
        float no_im = oi_re * ri_ + oi_im * rr_;

        constexpr float DTVEL = (float)(0.2 * 5e-7);
        constexpr float C1 = 0.70710678118654752f;                      // sqrt(0.5)
        constexpr float C2 = 1.6733200530681511e-07f;                   // sqrt(2*DT_TRANS)
        float t_re = DTVEL * oi_re + ((tn_re[i] * C1) * C2) * SDT;
        float t_im = DTVEL * oi_im + ((tn_im[i] * C1) * C2) * SDT;
        p0_re[i] = pi_re + t_re;
        p0_im[i] = pi_im + t_im;

        out[1 * 8192 + 2 * i]     = no_re;  out[1 * 8192 + 2 * i + 1] = no_im;
        out[2 * 8192 + 2 * i]     = o_re;   out[2 * 8192 + 2 * i + 1] = o_im;
        out[3 * 8192 + 2 * i]     = l_re;   out[3 * 8192 + 2 * i + 1] = l_im;
        out[4 * 8192 + 2 * i]     = r_re;   out[4 * 8192 + 2 * i + 1] = r_im;
    }
}

// ---------------- K3: one collision-resolution iteration ----------------
__global__ void k_coll(const float* __restrict__ pin_re, const float* __restrict__ pin_im,
                       float* __restrict__ pout_re, float* __restrict__ pout_im) {
    constexpr float TWO_RC  = (float)(2.0 * 3.15e-6);
    constexpr float TWO_RC2 = TWO_RC * TWO_RC;
    constexpr float C21RC   = (float)(2.1 * 3.15e-6);
    __shared__ float ls_re[256], ls_im[256];
    __shared__ float red[512];

    int tid = threadIdx.x;
    int li = tid & 15, sl = tid >> 4;
    int i = blockIdx.x * 16 + li;

    float pi_re = pin_re[i], pi_im = pin_im[i];
    float m_re = 0.0f, m_im = 0.0f;

    for (int c = 0; c < NPART / 256; ++c) {
        int j0 = c * 256;
        __syncthreads();
        ls_re[tid] = pin_re[j0 + tid];
        ls_im[tid] = pin_im[j0 + tid];
        __syncthreads();
#pragma unroll
        for (int t = 0; t < 16; ++t) {
            int jj = sl * 16 + t;
            int j = j0 + jj;
            float dr = ls_re[jj] - pi_re;   // diff = p_j - p_i
            float di = ls_im[jj] - pi_im;
            float d2 = dr * dr + di * di;
            if (d2 <= TWO_RC2 && j != i) {
                float a = sqrtf(d2);
                float m = (C21RC - a) * 0.5f / a;
                m_re += dr * m;
                m_im += di * m;
            }
        }
    }

    red[tid] = m_re; red[256 + tid] = m_im;
    __syncthreads();
    if (tid < 16) {
        for (int s = 1; s < 16; ++s) {
            int t2 = (s << 4) | tid;
            m_re += red[t2]; m_im += red[256 + t2];
        }
        pout_re[i] = pi_re - m_re;
        pout_im[i] = pi_im - m_im;
    }
}

// ---------------- K4: write new positions to out[0] ----------------
__global__ void k_copy(const float* __restrict__ pr, const float* __restrict__ pim,
                       float* __restrict__ out) {
    int i = blockIdx.x * 256 + threadIdx.x;
    out[2 * i]     = pr[i];
    out[2 * i + 1] = pim[i];
}

extern "C" void kernel_launch(void* const* d_in, const int* in_sizes, int n_in,
                              void* d_out, int out_size, void* d_ws, size_t ws_size,
                              hipStream_t stream) {
    const float* pos_re = (const float*)d_in[0];
    const float* pos_im = (const float*)d_in[1];
    const float* ori_re = (const float*)d_in[2];
    const float* ori_im = (const float*)d_in[3];
    const float* deltas = (const float*)d_in[4];
    const float* rot_noise = (const float*)d_in[5];
    const float* tn_re = (const float*)d_in[6];
    const float* tn_im = (const float*)d_in[7];
    float* out = (float*)d_out;
    float* ws = (float*)d_ws;

    float* ang   = ws;               // N
    float* cms   = ws + NPART;       // 2
    float* pA_re = ws + NPART + 2;   // N
    float* pA_im = pA_re + NPART;    // N
    float* pB_re = pA_im + NPART;    // N
    float* pB_im = pB_re + NPART;    // N

    k_ang<<<16, 256, 0, stream>>>(ori_re, ori_im, ang);
    k_cms<<<1, 256, 0, stream>>>(pos_re, pos_im, cms);
    k_interact<<<256, 256, 0, stream>>>(pos_re, pos_im, ori_re, ori_im, ang,
                                        deltas, rot_noise, tn_re, tn_im, cms,
                                        out, pA_re, pA_im);
    // 30 collision iterations (do-while is identity once collisions vanish)
    for (int it = 0; it < 30; ++it) {
        const float* ir = (it & 1) ? pB_re : pA_re;
        const float* ii = (it & 1) ? pB_im : pA_im;
        float* orr = (it & 1) ? pA_re : pB_re;
        float* ori = (it & 1) ? pA_im : pB_im;
        k_coll<<<256, 256, 0, stream>>>(ir, ii, orr, ori);
    }
    // 30 even -> final positions back in buffer A
    k_copy<<<16, 256, 0, stream>>>(pA_re, pA_im, out);
}

// Round 2
// 243.681 us; speedup vs baseline: 3.3485x; 3.3485x over previous
//
#include <hip/hip_runtime.h>

// ActiveParticles forward pass, N=4096, float32.
#define NPART 4096
#define PI_F 3.1415927410125732f
#define TWO_PI_F 6.2831854820251465f

__device__ __forceinline__ float wrapf(float d) {
    // replicates: d = where(d <= -PI, mod(d, PI), d); d -= (d >= PI)*2PI
    if (d <= -PI_F) {
        d = fmodf(d, PI_F);
        if (d < 0.0f) d += PI_F;     // python-mod sign fixup
    }
    if (d >= PI_F) d -= TWO_PI_F;
    return d;
}

// ---------------- K1: interaction pass (fused cms reduction) ----------------
// 256 blocks x 512 threads; block owns 16 i's; 32 j-slices of 16 per 512-chunk.
__global__ __launch_bounds__(512)
void k_interact(const float* __restrict__ pr, const float* __restrict__ pim,
                const float* __restrict__ orr, const float* __restrict__ oim,
                const float* __restrict__ deltas,
                const float* __restrict__ rot_noise,
                const float* __restrict__ tn_re, const float* __restrict__ tn_im,
                float* __restrict__ out, float2* __restrict__ p0) {
    constexpr float RR_F  = 8e-6f;
    constexpr float RR2   = RR_F * RR_F;
    constexpr float ROC_F = (float)(2.5e-5 + 3.15e-6);   // RO + RC
    constexpr float ROC2  = ROC_F * ROC_F;

    __shared__ float4 ls[512];                            // (pr, pim, or, oi) per j
    __shared__ float red_nr[512], red_sr[512], red_si[512], red_or[512], red_oi[512];
    __shared__ float c_re[512], c_im[512];

    int tid = threadIdx.x;
    int li = tid & 15, sl = tid >> 4;                     // sl in 0..31
    int i = blockIdx.x * 16 + li;

    float px = pr[i], py = pim[i];
    float ox = orr[i], oy = oim[i];

    float n_r = 0.0f, S_re = 0.0f, S_im = 0.0f, o_re = 0.0f, o_im = 0.0f;
    float cs_re = 0.0f, cs_im = 0.0f;

    for (int c = 0; c < 8; ++c) {
        int j0 = c * 512;
        __syncthreads();
        float jr = pr[j0 + tid], ji = pim[j0 + tid];
        ls[tid] = make_float4(jr, ji, orr[j0 + tid], oim[j0 + tid]);
        cs_re += jr; cs_im += ji;                         // each j staged exactly once
        __syncthreads();
#pragma unroll
        for (int t = 0; t < 16; ++t) {
            int jj = sl * 16 + ((t + 2 * sl) & 15);       // bank-swizzled read order
            int j = j0 + jj;
            float4 v = ls[jj];
            float dr = px - v.x;
            float di = py - v.y;
            float d2 = dr * dr + di * di;
            bool wro = d2 <= ROC2;                        // self included (d2=0)
            float dot = ox * v.z + oy * v.w;              // sign(cos(ai-aj)): in-front test
            bool wrr = (d2 <= RR2) & (dot > 0.0f) & (j != i);
            if (wro) { o_re += v.z; o_im += v.w; }
            if (wrr) { n_r += 1.0f; S_re += v.x; S_im += v.y; }
        }
    }

    red_nr[tid] = n_r; red_sr[tid] = S_re; red_si[tid] = S_im;
    red_or[tid] = o_re; red_oi[tid] = o_im;
    c_re[tid] = cs_re; c_im[tid] = cs_im;
    __syncthreads();
    // tree-reduce the global position sum (cms)
    for (int s = 256; s > 0; s >>= 1) {
        if (tid < s) { c_re[tid] += c_re[tid + s]; c_im[tid] += c_im[tid + s]; }
        __syncthreads();
    }

    if (tid < 16) {   // li == tid: per-particle epilogue
        for (int s = 1; s < 32; ++s) {
            int t2 = (s << 4) | tid;
            n_r += red_nr[t2]; S_re += red_sr[t2]; S_im += red_si[t2];
            o_re += red_or[t2]; o_im += red_oi[t2];
        }
        float maxnr = fmaxf(n_r, 1.0f);
        float sgn = (n_r > 0.0f) ? 1.0f : 0.0f;
        float Sre = S_re / maxnr - px * sgn;
        float Sim = S_im / maxnr - py * sgn;
        float d_re = -Sre, d_im = -Sim;

        float cmsx = c_re[0] * (1.0f / 4096.0f);
        float cmsy = c_im[0] * (1.0f / 4096.0f);
        float Ps_re = cmsx - px;                          // n_a = 4096 > 0
        float Ps_im = cmsy - py;

        float dl = deltas[i];
        float cd = cosf(dl), sd = sinf(dl);
        float l_re = Ps_re * cd - Ps_im * sd;             // Ps * e^{+i d}
        float l_im = Ps_re * sd + Ps_im * cd;
        float r_re = Ps_re * cd + Ps_im * sd;             // Ps * e^{-i d}
        float r_im = Ps_im * cd - Ps_re * sd;

        float nb   = fmaxf(hypotf(o_re, o_im), 1e-14f);
        float na_l = fmaxf(hypotf(l_re, l_im), 1e-14f);
        float na_r = fmaxf(hypotf(r_re, r_im), 1e-14f);
        float csl = (l_re * o_re + l_im * o_im) / (na_l * nb);
        float csr = (r_re * o_re + r_im * o_im) / (na_r * nb);
        float b_re = (csl >= csr) ? l_re : r_re;
        float b_im = (csl >= csr) ? l_im : r_im;

        float ai = atan2f(oy, ox);
        bool has_rep = (d_re != 0.0f) || (d_im != 0.0f);
        float att;
        if (has_rep) att = wrapf(atan2f(d_im, d_re) - ai);
        else         att = wrapf(atan2f(b_im, b_re) - ai);

        constexpr float GDD  = (float)(0.2 * 25.0 * 0.0028);  // DT*GAMMA*DR
        constexpr float S2DR = 0.07483314773547883f;           // sqrt(2*DR)
        constexpr float SDT  = 0.44721359549995793f;           // sqrt(DT)
        float theta = GDD * sinf(att) + (rot_noise[i] * S2DR) * SDT;
        float rr_ = cosf(theta), ri_ = sinf(theta);

        float no_re = ox * rr_ - oy * ri_;
        float no_im = ox * ri_ + oy * rr_;

        constexpr float DTVEL = (float)(0.2 * 5e-7);
        constexpr float C1 = 0.70710678118654752f;             // sqrt(0.5)
        constexpr float C2 = 1.6733200530681511e-07f;          // sqrt(2*DT_TRANS)
        float t_re = DTVEL * ox + ((tn_re[i] * C1) * C2) * SDT;
        float t_im = DTVEL * oy + ((tn_im[i] * C1) * C2) * SDT;
        p0[i] = make_float2(px + t_re, py + t_im);

        float2* o2 = (float2*)out;
        o2[1 * 4096 + i] = make_float2(no_re, no_im);
        o2[2 * 4096 + i] = make_float2(o_re, o_im);
        o2[3 * 4096 + i] = make_float2(l_re, l_im);
        o2[4 * 4096 + i] = make_float2(r_re, r_im);
    }
}

// ---------------- K2: one collision-resolution iteration (early-exit) ---------
__global__ __launch_bounds__(512)
void k_coll(const float2* __restrict__ pin, float2* __restrict__ pout,
            const int* __restrict__ cnt_prev, int* __restrict__ cnt_next,
            float2* __restrict__ outpos) {
    constexpr float TWO_RC  = (float)(2.0 * 3.15e-6);
    constexpr float TWO_RC2 = TWO_RC * TWO_RC;
    constexpr float C21RC   = (float)(2.1 * 3.15e-6);

    __shared__ float2 ls[512];
    __shared__ float rr_[512], ri_[512];
    __shared__ int rc_[512];

    int tid = threadIdx.x;
    int li = tid & 15, sl = tid >> 4;
    int i = blockIdx.x * 16 + li;

    bool active = (cnt_prev == nullptr) || (*cnt_prev > 0);
    if (!active) {                                       // converged: identity step
        if (tid < 16) {
            float2 p = pin[i];
            pout[i] = p;
            if (outpos) outpos[i] = p;
        }
        return;
    }

    float2 p = pin[i];
    float mre = 0.0f, mim = 0.0f;
    int nc = 0;

    for (int c = 0; c < 8; ++c) {
        int j0 = c * 512;
        __syncthreads();
        ls[tid] = pin[j0 + tid];
        __syncthreads();
#pragma unroll
        for (int t = 0; t < 16; ++t) {
            int jj = sl * 16 + ((t + 4 * sl) & 15);       // bank-swizzled
            int j = j0 + jj;
            float2 q = ls[jj];
            float dr = q.x - p.x;                         // diff = p_j - p_i
            float di = q.y - p.y;
            float d2 = dr * dr + di * di;
            if (d2 <= TWO_RC2 && j != i) {
                float a = sqrtf(d2);
                float m = (C21RC - a) * 0.5f / a;
                mre += dr * m; mim += di * m; ++nc;
            }
        }
    }

    rr_[tid] = mre; ri_[tid] = mim; rc_[tid] = nc;
    __syncthreads();
    if (tid < 16) {
        for (int s = 1; s < 32; ++s) {
            int t2 = (s << 4) | tid;
            mre += rr_[t2]; mim += ri_[t2]; nc += rc_[t2];
        }
        float2 np = make_float2(p.x - mre, p.y - mim);
        pout[i] = np;
        if (outpos) outpos[i] = np;
        rc_[tid] = nc;                                    // per-i collision counts
    }
    __syncthreads();
    if (tid == 0) {
        int tot = 0;
#pragma unroll
        for (int s = 0; s < 16; ++s) tot += rc_[s];
        if (tot > 0) atomicAdd(cnt_next, tot);
    }
}

extern "C" void kernel_launch(void* const* d_in, const int* in_sizes, int n_in,
                              void* d_out, int out_size, void* d_ws, size_t ws_size,
                              hipStream_t stream) {
    const float* pos_re = (const float*)d_in[0];
    const float* pos_im = (const float*)d_in[1];
    const float* ori_re = (const float*)d_in[2];
    const float* ori_im = (const float*)d_in[3];
    const float* deltas = (const float*)d_in[4];
    const float* rot_noise = (const float*)d_in[5];
    const float* tn_re = (const float*)d_in[6];
    const float* tn_im = (const float*)d_in[7];
    float* out = (float*)d_out;

    float2* pA = (float2*)d_ws;          // N
    float2* pB = pA + NPART;             // N
    int* cnt = (int*)(pB + NPART);       // 30 per-iteration collision counters

    hipMemsetAsync(cnt, 0, 32 * sizeof(int), stream);
    k_interact<<<256, 512, 0, stream>>>(pos_re, pos_im, ori_re, ori_im,
                                        deltas, rot_noise, tn_re, tn_im,
                                        out, pA);
    for (int it = 0; it < 30; ++it) {
        const float2* pin = (it & 1) ? pB : pA;
        float2* pout = (it & 1) ? pA : pB;
        const int* prev = it ? (cnt + it - 1) : nullptr;
        k_coll<<<256, 512, 0, stream>>>(pin, pout, prev, cnt + it,
                                        (it == 29) ? (float2*)out : nullptr);
    }
}